// Round 1
// baseline (3864.603 us; speedup 1.0000x reference)
//
#include <hip/hip_runtime.h>
#include <hip/hip_bf16.h>
#include <math.h>

#define S_ 8
#define B_ 64
#define T_ 64
#define N_ 16
#define FJ_ 32
#define H_ 128
#define MF_ 16
#define M_ 8
#define SB_ 512    // S*B
#define G1_ 32768  // S*B*T
#define G2_ 512    // B*M

#define XPAD 36    // padded stride for [16][32] tile
#define CPAD 132   // padded stride for [16][128] tile
#define PPAD 17    // padded stride for [16][16] tile

__device__ __forceinline__ float sigmoidf_(float x) { return 1.f / (1.f + __expf(-x)); }

__device__ __forceinline__ void fma8(float (&acc)[8], float xv, float4 wa, float4 wb) {
  acc[0] = fmaf(xv, wa.x, acc[0]);
  acc[1] = fmaf(xv, wa.y, acc[1]);
  acc[2] = fmaf(xv, wa.z, acc[2]);
  acc[3] = fmaf(xv, wa.w, acc[3]);
  acc[4] = fmaf(xv, wb.x, acc[4]);
  acc[5] = fmaf(xv, wb.y, acc[5]);
  acc[6] = fmaf(xv, wb.z, acc[6]);
  acc[7] = fmaf(xv, wb.w, acc[7]);
}

__device__ __forceinline__ float dot4_(float4 a, float4 b) {
  return fmaf(a.x, b.x, fmaf(a.y, b.y, fmaf(a.z, b.z, a.w * b.w)));
}

// 16-lane-group sum reduce (groups are lanes [16k,16k+15] of a wave)
__device__ __forceinline__ float grp16_sum(float v) {
#pragma unroll
  for (int m = 1; m < 16; m <<= 1) v += __shfl_xor(v, m);
  return v;
}
__device__ __forceinline__ float grp16_max(float v) {
#pragma unroll
  for (int m = 1; m < 16; m <<= 1) v = fmaxf(v, __shfl_xor(v, m));
  return v;
}

// layernorm over a 128-row distributed as 16 threads x 8 values
__device__ __forceinline__ void ln_row(float (&v)[8], const float* gw, const float* bw, int j0) {
  float s1 = 0.f, s2 = 0.f;
#pragma unroll
  for (int c = 0; c < 8; ++c) { s1 += v[c]; s2 += v[c] * v[c]; }
  s1 = grp16_sum(s1);
  s2 = grp16_sum(s2);
  float mu = s1 * (1.f / 128.f);
  float var = s2 * (1.f / 128.f) - mu * mu;
  float rstd = rsqrtf(var + 1e-5f);
#pragma unroll
  for (int c = 0; c < 8; ++c) v[c] = (v[c] - mu) * rstd * gw[j0 + c] + bw[j0 + c];
}

// ---------------------------------------------------------------------------
// Kernel A: job GAT encoder. One block per 16-node graph, 256 threads.
// out[g][j] = mean over nodes of 4-layer GAT stack.
// ---------------------------------------------------------------------------
__global__ __launch_bounds__(256) void gat_job_kernel(
    const float* __restrict__ xin,   // [G,16,32]
    const int* __restrict__ adjin,   // [G,16,16]
    const float* __restrict__ W0,    // [32,128]
    const float* __restrict__ W123,  // [3,128,128]
    const float* __restrict__ avec,  // [4,256]
    float* __restrict__ outm)        // [G,128]
{
  __shared__ __align__(16) float xls[16 * XPAD];
  __shared__ __align__(16) float cur[16 * CPAD];
  __shared__ __align__(16) float tmp[16 * CPAD];
  __shared__ float pm[16 * PPAD];
  __shared__ float f1s[16], f2s[16];
  __shared__ int adjs[16 * 16];

  const int g = blockIdx.x;
  const int tid = threadIdx.x;

  // load x [16][32] (128 float4) into padded LDS
  if (tid < 128) {
    int r = tid >> 3, c4 = tid & 7;
    const float4* xg = (const float4*)(xin + (size_t)g * 512);
    *(float4*)(xls + r * XPAD + c4 * 4) = xg[tid];
  }
  adjs[tid] = adjin[(size_t)g * 256 + tid];
  __syncthreads();

  const int i = tid >> 4;   // row 0..15
  const int jb = tid & 15;  // col-block 0..15
  const int j0 = jb << 3;

  for (int layer = 0; layer < 4; ++layer) {
    const float* W = (layer == 0) ? W0 : (W123 + (size_t)(layer - 1) * H_ * H_);
    const float* a0 = avec + layer * 256;
    const float* a1 = a0 + 128;

    // ---- h = x @ W  (acc = h[i][j0..j0+7]) ----
    float acc[8];
#pragma unroll
    for (int c = 0; c < 8; ++c) acc[c] = 0.f;
    if (layer == 0) {
#pragma unroll 4
      for (int k = 0; k < FJ_; ++k) {
        float xv = xls[i * XPAD + k];
        float4 wa = *(const float4*)(W + (size_t)k * H_ + j0);
        float4 wb = *(const float4*)(W + (size_t)k * H_ + j0 + 4);
        fma8(acc, xv, wa, wb);
      }
    } else {
#pragma unroll 4
      for (int k = 0; k < H_; ++k) {
        float xv = cur[i * CPAD + k];
        float4 wa = *(const float4*)(W + (size_t)k * H_ + j0);
        float4 wb = *(const float4*)(W + (size_t)k * H_ + j0 + 4);
        fma8(acc, xv, wa, wb);
      }
    }
    // store h to tmp
    *(float4*)(tmp + i * CPAD + j0) = make_float4(acc[0], acc[1], acc[2], acc[3]);
    *(float4*)(tmp + i * CPAD + j0 + 4) = make_float4(acc[4], acc[5], acc[6], acc[7]);

    // ---- f1[i] = h[i]·a0 , f2[i] = h[i]·a1 ----
    float p1 = 0.f, p2 = 0.f;
#pragma unroll
    for (int c = 0; c < 8; ++c) {
      p1 = fmaf(acc[c], a0[j0 + c], p1);
      p2 = fmaf(acc[c], a1[j0 + c], p2);
    }
    p1 = grp16_sum(p1);
    p2 = grp16_sum(p2);
    if (jb == 0) { f1s[i] = p1; f2s[i] = p2; }
    __syncthreads();

    // ---- e[i][jc] -> masked leaky-relu -> softmax row ----
    {
      int jc = jb;  // thread (i, jc): 16x16 exactly
      float e = f1s[i] + f2s[jc];
      e = (e >= 0.f) ? e : 0.2f * e;
      if (adjs[i * 16 + jc] <= 0) e = -1e9f;
      float mx = grp16_max(e);
      float ex = __expf(e - mx);
      float sm = grp16_sum(ex);
      pm[i * PPAD + jc] = ex / sm;
    }
    __syncthreads();

    // ---- out = p @ h (+ residual) -> tanh -> cur ----
    float o[8];
#pragma unroll
    for (int c = 0; c < 8; ++c) o[c] = 0.f;
#pragma unroll
    for (int k = 0; k < 16; ++k) {
      float pv = pm[i * PPAD + k];
      float4 ha = *(const float4*)(tmp + k * CPAD + j0);
      float4 hb = *(const float4*)(tmp + k * CPAD + j0 + 4);
      fma8(o, pv, ha, hb);
    }
#pragma unroll
    for (int c = 0; c < 8; ++c) {
      float v = o[c] + ((layer > 0) ? cur[i * CPAD + j0 + c] : 0.f);
      cur[i * CPAD + j0 + c] = tanhf(v);
    }
    __syncthreads();
  }

  // mean over 16 nodes
  if (tid < 128) {
    float s = 0.f;
#pragma unroll
    for (int r = 0; r < 16; ++r) s += cur[r * CPAD + tid];
    outm[(size_t)g * H_ + tid] = s * (1.f / 16.f);
  }
}

// ---------------------------------------------------------------------------
// Kernel B: xs[t][seq][gate] = emb[seq][t][:] . Wih[gate][:] + b[gate]
// 16 rows per block, 512 threads (one gate each), Wih row in registers.
// ---------------------------------------------------------------------------
__global__ __launch_bounds__(512) void xs_kernel(
    const float* __restrict__ emb,   // [SB*T,128]
    const float* __restrict__ Wih,   // [512,128]
    const float* __restrict__ bvec,  // [512]
    float* __restrict__ xs)          // [T,SB,512]
{
  __shared__ __align__(16) float es[16 * CPAD];
  const int tid = threadIdx.x;
  const int rb = blockIdx.x;

  {
    int r = tid >> 5, c4 = tid & 31;
    const float4* src = (const float4*)(emb + ((size_t)rb * 16 + r) * H_);
    *(float4*)(es + r * CPAD + c4 * 4) = src[c4];
  }
  __syncthreads();

  float4 w[32];
  const float4* wr = (const float4*)(Wih + (size_t)tid * H_);
#pragma unroll
  for (int q = 0; q < 32; ++q) w[q] = wr[q];
  float bj = bvec[tid];

  for (int r = 0; r < 16; ++r) {
    float acc = bj;
    const float* er = es + r * CPAD;
#pragma unroll
    for (int q = 0; q < 32; ++q) acc += dot4_(*(const float4*)(er + q * 4), w[q]);
    int row = rb * 16 + r;  // row = seq*T + t
    int t = row & (T_ - 1);
    int seq = row >> 6;
    xs[((size_t)t * SB_ + seq) * 512 + tid] = acc;
  }
}

// ---------------------------------------------------------------------------
// Kernel C: LSTM recurrence. One block per sequence, 512 threads (one gate
// each, Whh row register-cached). Threads 0..127 own cell state.
// ---------------------------------------------------------------------------
__global__ __launch_bounds__(512) void lstm_kernel(
    const float* __restrict__ xs,   // [T,SB,512]
    const float* __restrict__ Whh,  // [512,128]
    float* __restrict__ hlast)      // [SB,128]
{
  __shared__ __align__(16) float hs[128];
  __shared__ float gs[512];
  const int seq = blockIdx.x;
  const int j = threadIdx.x;

  float4 w[32];
  const float4* wr = (const float4*)(Whh + (size_t)j * H_);
#pragma unroll
  for (int q = 0; q < 32; ++q) w[q] = wr[q];

  float c = 0.f;
  if (j < 128) hs[j] = 0.f;
  __syncthreads();

  for (int t = 0; t < T_; ++t) {
    float acc = xs[((size_t)t * SB_ + seq) * 512 + j];
    const float* hp = hs;
#pragma unroll
    for (int q = 0; q < 32; ++q) acc += dot4_(*(const float4*)(hp + q * 4), w[q]);
    gs[j] = acc;
    __syncthreads();
    if (j < 128) {
      float ig = gs[j], fg = gs[128 + j], gg = gs[256 + j], og = gs[384 + j];
      c = sigmoidf_(fg) * c + sigmoidf_(ig) * tanhf(gg);
      hs[j] = sigmoidf_(og) * tanhf(c);
    }
    __syncthreads();
  }
  if (j < 128) hlast[(size_t)seq * H_ + j] = hs[j];
}

// ---------------------------------------------------------------------------
// Kernel D: fused machine-side pipeline. One block per batch element b.
// ---------------------------------------------------------------------------
__global__ __launch_bounds__(256) void machine_kernel(
    const float* __restrict__ machine_f,  // [B,16,16]
    const int* __restrict__ machine_a,    // [B,16,16]
    const float* __restrict__ hlast,      // [SB,128] (seq = s*B+b)
    const float* __restrict__ jm,         // [B*M,128]
    const float* __restrict__ mfe_W, const float* __restrict__ mfe_b,
    const float* __restrict__ n2_g, const float* __restrict__ n2_b,
    const float* __restrict__ me_W, const float* __restrict__ me_b,
    const float* __restrict__ n3_g, const float* __restrict__ n3_b,
    const float* __restrict__ mgW,  // [4,128,128]
    const float* __restrict__ mga,  // [4,256]
    const float* __restrict__ mng, const float* __restrict__ mnb,  // [4,128]
    float* __restrict__ outp)  // [B,128]
{
  __shared__ float mf[256];
  __shared__ int adjs[256];
  __shared__ __align__(16) float ctx[16 * CPAD];
  __shared__ __align__(16) float mfh[16 * CPAD];
  __shared__ __align__(16) float cur[16 * CPAD];
  __shared__ __align__(16) float tmp[16 * CPAD];
  __shared__ __align__(16) float prevb[16 * CPAD];
  __shared__ float pm[16 * PPAD];
  __shared__ float f1s[16], f2s[16];

  const int b = blockIdx.x;
  const int tid = threadIdx.x;
  const int i = tid >> 4;
  const int jb = tid & 15;
  const int j0 = jb << 3;

  mf[tid] = machine_f[(size_t)b * 256 + tid];
  adjs[tid] = machine_a[(size_t)b * 256 + tid];
  // ctx: rows 0..7 stage contexts (hlast), rows 8..15 machine contexts (jm)
  {
    const float* src = (i < 8) ? (hlast + ((size_t)i * B_ + b) * H_)
                               : (jm + ((size_t)b * M_ + (i - 8)) * H_);
    float4 c1 = ((const float4*)src)[jb * 2];
    float4 c2 = ((const float4*)src)[jb * 2 + 1];
    *(float4*)(ctx + i * CPAD + j0) = c1;
    *(float4*)(ctx + i * CPAD + j0 + 4) = c2;
  }
  __syncthreads();

  // ---- mfh = tanh(LN(machine_f @ mfe_W + mfe_b)) ----
  {
    float acc[8];
#pragma unroll
    for (int c = 0; c < 8; ++c) acc[c] = 0.f;
#pragma unroll
    for (int k = 0; k < MF_; ++k) {
      float xv = mf[i * 16 + k];
      float4 wa = *(const float4*)(mfe_W + (size_t)k * H_ + j0);
      float4 wb = *(const float4*)(mfe_W + (size_t)k * H_ + j0 + 4);
      fma8(acc, xv, wa, wb);
    }
#pragma unroll
    for (int c = 0; c < 8; ++c) acc[c] += mfe_b[j0 + c];
    ln_row(acc, n2_g, n2_b, j0);
#pragma unroll
    for (int c = 0; c < 8; ++c) mfh[i * CPAD + j0 + c] = tanhf(acc[c]);
  }
  __syncthreads();

  // ---- nodes = tanh(LN(concat(mfh,ctx) @ me_W + me_b)) ----
  {
    float acc[8];
#pragma unroll
    for (int c = 0; c < 8; ++c) acc[c] = 0.f;
#pragma unroll 4
    for (int k = 0; k < H_; ++k) {
      float xv = mfh[i * CPAD + k];
      float4 wa = *(const float4*)(me_W + (size_t)k * H_ + j0);
      float4 wb = *(const float4*)(me_W + (size_t)k * H_ + j0 + 4);
      fma8(acc, xv, wa, wb);
    }
#pragma unroll 4
    for (int k = 0; k < H_; ++k) {
      float xv = ctx[i * CPAD + k];
      float4 wa = *(const float4*)(me_W + (size_t)(128 + k) * H_ + j0);
      float4 wb = *(const float4*)(me_W + (size_t)(128 + k) * H_ + j0 + 4);
      fma8(acc, xv, wa, wb);
    }
#pragma unroll
    for (int c = 0; c < 8; ++c) acc[c] += me_b[j0 + c];
    ln_row(acc, n3_g, n3_b, j0);
#pragma unroll
    for (int c = 0; c < 8; ++c) cur[i * CPAD + j0 + c] = tanhf(acc[c]);
  }
  __syncthreads();

  // ---- 4 machine GAT layers: h = tanh(LN(gat(h)) [+ prev]) ----
  for (int l = 0; l < 4; ++l) {
    const float* W = mgW + (size_t)l * H_ * H_;
    const float* a0 = mga + l * 256;
    const float* a1 = a0 + 128;

    float acc[8];
#pragma unroll
    for (int c = 0; c < 8; ++c) acc[c] = 0.f;
#pragma unroll 4
    for (int k = 0; k < H_; ++k) {
      float xv = cur[i * CPAD + k];
      float4 wa = *(const float4*)(W + (size_t)k * H_ + j0);
      float4 wb = *(const float4*)(W + (size_t)k * H_ + j0 + 4);
      fma8(acc, xv, wa, wb);
    }
    *(float4*)(tmp + i * CPAD + j0) = make_float4(acc[0], acc[1], acc[2], acc[3]);
    *(float4*)(tmp + i * CPAD + j0 + 4) = make_float4(acc[4], acc[5], acc[6], acc[7]);

    float p1 = 0.f, p2 = 0.f;
#pragma unroll
    for (int c = 0; c < 8; ++c) {
      p1 = fmaf(acc[c], a0[j0 + c], p1);
      p2 = fmaf(acc[c], a1[j0 + c], p2);
    }
    p1 = grp16_sum(p1);
    p2 = grp16_sum(p2);
    if (jb == 0) { f1s[i] = p1; f2s[i] = p2; }
    __syncthreads();

    {
      int jc = jb;
      float e = f1s[i] + f2s[jc];
      e = (e >= 0.f) ? e : 0.2f * e;
      if (adjs[i * 16 + jc] <= 0) e = -1e9f;
      float mx = grp16_max(e);
      float ex = __expf(e - mx);
      float sm = grp16_sum(ex);
      pm[i * PPAD + jc] = ex / sm;
    }
    __syncthreads();

    float o[8];
#pragma unroll
    for (int c = 0; c < 8; ++c) o[c] = 0.f;
#pragma unroll
    for (int k = 0; k < 16; ++k) {
      float pv = pm[i * PPAD + k];
      float4 ha = *(const float4*)(tmp + k * CPAD + j0);
      float4 hb = *(const float4*)(tmp + k * CPAD + j0 + 4);
      fma8(o, pv, ha, hb);
    }
    ln_row(o, mng + l * H_, mnb + l * H_, j0);
#pragma unroll
    for (int c = 0; c < 8; ++c) {
      float v = o[c] + ((l > 0) ? prevb[i * CPAD + j0 + c] : 0.f);
      v = tanhf(v);
      cur[i * CPAD + j0 + c] = v;
      prevb[i * CPAD + j0 + c] = v;
    }
    __syncthreads();
  }

  if (tid < 128) {
    float s = 0.f;
#pragma unroll
    for (int r = 0; r < 16; ++r) s += cur[r * CPAD + tid];
    outp[(size_t)b * H_ + tid] = s * (1.f / 16.f);
  }
}

// ---------------------------------------------------------------------------
extern "C" void kernel_launch(void* const* d_in, const int* in_sizes, int n_in,
                              void* d_out, int out_size, void* d_ws, size_t ws_size,
                              hipStream_t stream) {
  const float* j_stages_f  = (const float*)d_in[0];
  const int*   j_stages_a  = (const int*)d_in[1];
  const float* j_machine_f = (const float*)d_in[2];
  const int*   j_machine_a = (const int*)d_in[3];
  const float* machine_f   = (const float*)d_in[4];
  const int*   machine_a   = (const int*)d_in[5];
  const float* jg1_W       = (const float*)d_in[6];
  const float* jgW         = (const float*)d_in[7];
  const float* jga         = (const float*)d_in[8];
  const float* lstm_Wih    = (const float*)d_in[9];
  const float* lstm_Whh    = (const float*)d_in[10];
  const float* lstm_b      = (const float*)d_in[11];
  const float* mfe_W       = (const float*)d_in[12];
  const float* mfe_b       = (const float*)d_in[13];
  const float* n2_g        = (const float*)d_in[14];
  const float* n2_b        = (const float*)d_in[15];
  const float* me_W        = (const float*)d_in[16];
  const float* me_b        = (const float*)d_in[17];
  const float* n3_g        = (const float*)d_in[18];
  const float* n3_b        = (const float*)d_in[19];
  const float* mgW         = (const float*)d_in[20];
  const float* mga         = (const float*)d_in[21];
  const float* mng         = (const float*)d_in[22];
  const float* mnb         = (const float*)d_in[23];
  float* out = (float*)d_out;

  // workspace layout (floats): stage_emb | jm | hlast | xs
  float* stage_emb = (float*)d_ws;                  // G1*128   = 16.78 MB
  float* jm        = stage_emb + (size_t)G1_ * H_;  // G2*128   =  0.26 MB
  float* hlast     = jm + (size_t)G2_ * H_;         // SB*128   =  0.26 MB
  float* xs        = hlast + (size_t)SB_ * H_;      // T*SB*512 = 67.1 MB

  gat_job_kernel<<<G1_, 256, 0, stream>>>(j_stages_f, j_stages_a, jg1_W, jgW, jga, stage_emb);
  gat_job_kernel<<<G2_, 256, 0, stream>>>(j_machine_f, j_machine_a, jg1_W, jgW, jga, jm);
  xs_kernel<<<G1_ / 16, 512, 0, stream>>>(stage_emb, lstm_Wih, lstm_b, xs);
  lstm_kernel<<<SB_, 512, 0, stream>>>(xs, lstm_Whh, hlast);
  machine_kernel<<<B_, 256, 0, stream>>>(machine_f, machine_a, hlast, jm,
                                         mfe_W, mfe_b, n2_g, n2_b, me_W, me_b,
                                         n3_g, n3_b, mgW, mga, mng, mnb, out);
}

// Round 2
// 1000.413 us; speedup vs baseline: 3.8630x; 3.8630x over previous
//
#include <hip/hip_runtime.h>
#include <hip/hip_bf16.h>
#include <math.h>

#define S_ 8
#define B_ 64
#define T_ 64
#define N_ 16
#define FJ_ 32
#define H_ 128
#define MF_ 16
#define M_ 8
#define SB_ 512    // S*B
#define G1_ 32768  // S*B*T
#define G2_ 512    // B*M

#define CPAD 132   // padded stride for [16][128] f32 tile (other kernels)
#define PPAD 17

typedef short bf16x8 __attribute__((ext_vector_type(8)));
typedef float f32x4 __attribute__((ext_vector_type(4)));
typedef unsigned short u16;

__device__ __forceinline__ u16 f2bf(float f) {
  union { float f; unsigned u; } v; v.f = f;
  unsigned r = v.u + 0x7FFFu + ((v.u >> 16) & 1u);
  return (u16)(r >> 16);
}
__device__ __forceinline__ unsigned packbf2(float lo, float hi) {
  return (unsigned)f2bf(lo) | ((unsigned)f2bf(hi) << 16);
}
__device__ __forceinline__ float ftanh(float x) {
  float e = __expf(2.f * x);
  return 1.f - 2.f / (e + 1.f);
}
__device__ __forceinline__ float sigmoidf_(float x) { return 1.f / (1.f + __expf(-x)); }

__device__ __forceinline__ float dot4_(float4 a, float4 b) {
  return fmaf(a.x, b.x, fmaf(a.y, b.y, fmaf(a.z, b.z, a.w * b.w)));
}
__device__ __forceinline__ void fma8(float (&acc)[8], float xv, float4 wa, float4 wb) {
  acc[0] = fmaf(xv, wa.x, acc[0]); acc[1] = fmaf(xv, wa.y, acc[1]);
  acc[2] = fmaf(xv, wa.z, acc[2]); acc[3] = fmaf(xv, wa.w, acc[3]);
  acc[4] = fmaf(xv, wb.x, acc[4]); acc[5] = fmaf(xv, wb.y, acc[5]);
  acc[6] = fmaf(xv, wb.z, acc[6]); acc[7] = fmaf(xv, wb.w, acc[7]);
}
__device__ __forceinline__ float grp16_sum(float v) {
#pragma unroll
  for (int m = 1; m < 16; m <<= 1) v += __shfl_xor(v, m);
  return v;
}
__device__ __forceinline__ float grp16_max(float v) {
#pragma unroll
  for (int m = 1; m < 16; m <<= 1) v = fmaxf(v, __shfl_xor(v, m));
  return v;
}
__device__ __forceinline__ void ln_row(float (&v)[8], const float* gw, const float* bw, int j0) {
  float s1 = 0.f, s2 = 0.f;
#pragma unroll
  for (int c = 0; c < 8; ++c) { s1 += v[c]; s2 += v[c] * v[c]; }
  s1 = grp16_sum(s1); s2 = grp16_sum(s2);
  float mu = s1 * (1.f / 128.f);
  float var = s2 * (1.f / 128.f) - mu * mu;
  float rstd = rsqrtf(var + 1e-5f);
#pragma unroll
  for (int c = 0; c < 8; ++c) v[c] = (v[c] - mu) * rstd * gw[j0 + c] + bw[j0 + c];
}

// ---------------------------------------------------------------------------
// Pre-pack W0 [32][128] and W123 [3][128][128] into per-lane MFMA B-fragment
// order (bf16): wpk0[(n*64+l)*8+e] = W0[(l>>4)*8+e][16n+(l&15)]
//               wpkL[(((layer*8+n)*4+kk)*64+l)*8+e] = W[kk*32+(l>>4)*8+e][16n+(l&15)]
// ---------------------------------------------------------------------------
__global__ __launch_bounds__(256) void pack_w_kernel(
    const float* __restrict__ W0, const float* __restrict__ W123,
    u16* __restrict__ wpk0, u16* __restrict__ wpkL) {
  int idx = blockIdx.x * 256 + threadIdx.x;
  if (idx < 4096) {
    int e = idx & 7, l = (idx >> 3) & 63, n = idx >> 9;
    int k = (l >> 4) * 8 + e, col = 16 * n + (l & 15);
    wpk0[idx] = f2bf(W0[k * 128 + col]);
  } else if (idx < 4096 + 49152) {
    int id = idx - 4096;
    int e = id & 7, l = (id >> 3) & 63, kk = (id >> 9) & 3, n = (id >> 11) & 7, layer = id >> 14;
    int k = kk * 32 + (l >> 4) * 8 + e, col = 16 * n + (l & 15);
    wpkL[id] = f2bf(W123[(layer * 128 + k) * 128 + col]);
  }
}

// ---------------------------------------------------------------------------
// GAT encoder, MFMA version: ONE WAVE PER GRAPH (4 graphs / 256-thr block).
// No __syncthreads anywhere — all staging is per-wave.
// ---------------------------------------------------------------------------
__global__ __launch_bounds__(256) void gat_mfma_kernel(
    const float* __restrict__ xin,   // [G,16,32]
    const int* __restrict__ adjin,   // [G,16,16]
    const u16* __restrict__ wpk0,    // packed layer-0 W
    const u16* __restrict__ wpkL,    // packed layer-1..3 W
    const float* __restrict__ avec,  // [4,256]
    float* __restrict__ outm)        // [G,128]
{
  __shared__ __align__(16) u16 curls[4][16 * 136];  // per-wave bf16 activation
  __shared__ __align__(16) float fbuf[4][32];       // per-wave f1/f2 broadcast

  const int wv = threadIdx.x >> 6;
  const int l  = threadIdx.x & 63;
  const int g  = blockIdx.x * 4 + wv;
  const int c  = l & 15;   // A-row / B-col / C-col index
  const int q  = l >> 4;   // k-group / C-row-group
  const int qq = q & 1;
  u16* cw = curls[wv];
  float* fb = fbuf[wv];

  // adjacency mask bits: row i=c, cols j = 8*qq + e
  int adjm;
  {
    const int* ar = adjin + (size_t)g * 256 + c * 16 + 8 * qq;
    int4 A1 = *(const int4*)ar;
    int4 A2 = *(const int4*)(ar + 4);
    adjm = (A1.x > 0) | ((A1.y > 0) << 1) | ((A1.z > 0) << 2) | ((A1.w > 0) << 3) |
           ((A2.x > 0) << 4) | ((A2.y > 0) << 5) | ((A2.z > 0) << 6) | ((A2.w > 0) << 7);
  }

  f32x4 res[8];  // C-layout activation (residual), f32
#pragma unroll
  for (int n = 0; n < 8; ++n) res[n] = (f32x4){0.f, 0.f, 0.f, 0.f};

#pragma unroll 1
  for (int layer = 0; layer < 4; ++layer) {
    // ---- A-fragments of current activation ----
    bf16x8 afr[4];
    const u16* wl;
    if (layer == 0) {
      wl = wpk0;
      const float* xg = xin + (size_t)g * 512 + c * 32 + q * 8;
      float4 x1 = *(const float4*)xg;
      float4 x2 = *(const float4*)(xg + 4);
      union { bf16x8 v; u16 s[8]; } u;
      u.s[0] = f2bf(x1.x); u.s[1] = f2bf(x1.y); u.s[2] = f2bf(x1.z); u.s[3] = f2bf(x1.w);
      u.s[4] = f2bf(x2.x); u.s[5] = f2bf(x2.y); u.s[6] = f2bf(x2.z); u.s[7] = f2bf(x2.w);
      afr[0] = u.v;
    } else {
      wl = wpkL + (size_t)(layer - 1) * 16384;
#pragma unroll
      for (int kk = 0; kk < 4; ++kk)
        afr[kk] = *(const bf16x8*)(cw + c * 136 + kk * 32 + q * 8);
    }

    // ---- h = x @ W via MFMA (C-layout: lane holds h[4q+r][16n+c]) ----
    f32x4 hacc[8];
    if (layer == 0) {
#pragma unroll
      for (int n = 0; n < 8; ++n) {
        f32x4 acc = (f32x4){0.f, 0.f, 0.f, 0.f};
        bf16x8 wf = *(const bf16x8*)(wl + ((size_t)n * 64 + l) * 8);
        acc = __builtin_amdgcn_mfma_f32_16x16x32_bf16(afr[0], wf, acc, 0, 0, 0);
        hacc[n] = acc;
      }
    } else {
#pragma unroll
      for (int n = 0; n < 8; ++n) {
        f32x4 acc = (f32x4){0.f, 0.f, 0.f, 0.f};
#pragma unroll
        for (int kk = 0; kk < 4; ++kk) {
          bf16x8 wf = *(const bf16x8*)(wl + ((size_t)(n * 4 + kk) * 64 + l) * 8);
          acc = __builtin_amdgcn_mfma_f32_16x16x32_bf16(afr[kk], wf, acc, 0, 0, 0);
        }
        hacc[n] = acc;
      }
    }

    // ---- f1/f2 partials (f32) + pack h rows to bf16 dword pairs ----
    const float* a0 = avec + layer * 256;
    const float* a1 = a0 + 128;
    float f1l[4] = {0.f, 0.f, 0.f, 0.f};
    float f2l[4] = {0.f, 0.f, 0.f, 0.f};
    unsigned hp0[8], hp1[8];
#pragma unroll
    for (int n = 0; n < 8; ++n) {
      float av0 = a0[16 * n + c];
      float av1 = a1[16 * n + c];
      f32x4 h = hacc[n];
#pragma unroll
      for (int r = 0; r < 4; ++r) {
        f1l[r] = fmaf(h[r], av0, f1l[r]);
        f2l[r] = fmaf(h[r], av1, f2l[r]);
      }
      hp0[n] = packbf2(h[0], h[1]);  // rows 4q+0,4q+1 at col 16n+c
      hp1[n] = packbf2(h[2], h[3]);  // rows 4q+2,4q+3
    }
#pragma unroll
    for (int m = 1; m < 16; m <<= 1) {
#pragma unroll
      for (int r = 0; r < 4; ++r) {
        f1l[r] += __shfl_xor(f1l[r], m);
        f2l[r] += __shfl_xor(f2l[r], m);
      }
    }
    if (c == 0) {
      *(float4*)&fb[4 * q]      = make_float4(f1l[0], f1l[1], f1l[2], f1l[3]);
      *(float4*)&fb[16 + 4 * q] = make_float4(f2l[0], f2l[1], f2l[2], f2l[3]);
    }

    // ---- softmax row i=c over j, laid out as P A-fragment (k=8q+e) ----
    float f1v = fb[c];
    float4 f2a = *(const float4*)&fb[16 + 8 * qq];
    float4 f2b = *(const float4*)&fb[16 + 8 * qq + 4];
    float ev[8] = {f1v + f2a.x, f1v + f2a.y, f1v + f2a.z, f1v + f2a.w,
                   f1v + f2b.x, f1v + f2b.y, f1v + f2b.z, f1v + f2b.w};
#pragma unroll
    for (int e = 0; e < 8; ++e) {
      float v = ev[e];
      v = (v >= 0.f) ? v : 0.2f * v;
      ev[e] = ((adjm >> e) & 1) ? v : -1e9f;
    }
    float mx = ev[0];
#pragma unroll
    for (int e = 1; e < 8; ++e) mx = fmaxf(mx, ev[e]);
    mx = fmaxf(mx, __shfl_xor(mx, 16));
    float sm = 0.f;
#pragma unroll
    for (int e = 0; e < 8; ++e) { ev[e] = __expf(ev[e] - mx); sm += ev[e]; }
    sm += __shfl_xor(sm, 16);
    float zinv = (q < 2) ? (1.f / sm) : 0.f;  // groups 2,3 hold K-padding zeros
    union { bf16x8 v; u16 s[8]; } pu;
#pragma unroll
    for (int e = 0; e < 8; ++e) pu.s[e] = f2bf(ev[e] * zinv);
    bf16x8 pfrag = pu.v;

    // ---- O = P @ h (+residual) -> tanh; B-frag via 4 shfls per n-tile ----
    const int s0 = c + 16 * ((2 * q) & 3);
    const int s1 = c + 16 * ((2 * q + 1) & 3);
#pragma unroll
    for (int n = 0; n < 8; ++n) {
      union { bf16x8 v; unsigned u[4]; } bu;
      bu.u[0] = __shfl(hp0[n], s0);  // rows 8q+0,1
      bu.u[1] = __shfl(hp1[n], s0);  // rows 8q+2,3
      bu.u[2] = __shfl(hp0[n], s1);  // rows 8q+4,5
      bu.u[3] = __shfl(hp1[n], s1);  // rows 8q+6,7
      f32x4 o = (layer > 0) ? res[n] : (f32x4){0.f, 0.f, 0.f, 0.f};
      o = __builtin_amdgcn_mfma_f32_16x16x32_bf16(pfrag, bu.v, o, 0, 0, 0);
      f32x4 t;
      t[0] = ftanh(o[0]); t[1] = ftanh(o[1]); t[2] = ftanh(o[2]); t[3] = ftanh(o[3]);
      res[n] = t;
      if (layer < 3) {
#pragma unroll
        for (int r = 0; r < 4; ++r)
          cw[(4 * q + r) * 136 + 16 * n + c] = f2bf(t[r]);
      }
    }
  }

  // ---- mean over 16 nodes ----
#pragma unroll
  for (int n = 0; n < 8; ++n) {
    float s = res[n][0] + res[n][1] + res[n][2] + res[n][3];
    s += __shfl_xor(s, 16);
    s += __shfl_xor(s, 32);
    if (q == 0) outm[(size_t)g * 128 + 16 * n + c] = s * 0.0625f;
  }
}

// ---------------------------------------------------------------------------
// Kernel B: xs[t][seq][gate] = emb[seq][t][:] . Wih[gate][:] + b[gate]
// ---------------------------------------------------------------------------
__global__ __launch_bounds__(512) void xs_kernel(
    const float* __restrict__ emb,   // [SB*T,128]
    const float* __restrict__ Wih,   // [512,128]
    const float* __restrict__ bvec,  // [512]
    float* __restrict__ xs)          // [T,SB,512]
{
  __shared__ __align__(16) float es[16 * CPAD];
  const int tid = threadIdx.x;
  const int rb = blockIdx.x;
  {
    int r = tid >> 5, c4 = tid & 31;
    const float4* src = (const float4*)(emb + ((size_t)rb * 16 + r) * H_);
    *(float4*)(es + r * CPAD + c4 * 4) = src[c4];
  }
  __syncthreads();

  float4 w[32];
  const float4* wr = (const float4*)(Wih + (size_t)tid * H_);
#pragma unroll
  for (int q = 0; q < 32; ++q) w[q] = wr[q];
  float bj = bvec[tid];

  for (int r = 0; r < 16; ++r) {
    float acc = bj;
    const float* er = es + r * CPAD;
#pragma unroll
    for (int q = 0; q < 32; ++q) acc += dot4_(*(const float4*)(er + q * 4), w[q]);
    int row = rb * 16 + r;
    int t = row & (T_ - 1);
    int seq = row >> 6;
    xs[((size_t)t * SB_ + seq) * 512 + tid] = acc;
  }
}

// ---------------------------------------------------------------------------
// Kernel C: LSTM recurrence
// ---------------------------------------------------------------------------
__global__ __launch_bounds__(512) void lstm_kernel(
    const float* __restrict__ xs,   // [T,SB,512]
    const float* __restrict__ Whh,  // [512,128]
    float* __restrict__ hlast)      // [SB,128]
{
  __shared__ __align__(16) float hs[128];
  __shared__ float gs[512];
  const int seq = blockIdx.x;
  const int j = threadIdx.x;

  float4 w[32];
  const float4* wr = (const float4*)(Whh + (size_t)j * H_);
#pragma unroll
  for (int q = 0; q < 32; ++q) w[q] = wr[q];

  float c = 0.f;
  if (j < 128) hs[j] = 0.f;
  __syncthreads();

  for (int t = 0; t < T_; ++t) {
    float acc = xs[((size_t)t * SB_ + seq) * 512 + j];
#pragma unroll
    for (int q = 0; q < 32; ++q) acc += dot4_(*(const float4*)(hs + q * 4), w[q]);
    gs[j] = acc;
    __syncthreads();
    if (j < 128) {
      float ig = gs[j], fg = gs[128 + j], gg = gs[256 + j], og = gs[384 + j];
      c = sigmoidf_(fg) * c + sigmoidf_(ig) * tanhf(gg);
      hs[j] = sigmoidf_(og) * tanhf(c);
    }
    __syncthreads();
  }
  if (j < 128) hlast[(size_t)seq * H_ + j] = hs[j];
}

// ---------------------------------------------------------------------------
// Kernel D: fused machine-side pipeline. One block per batch element b.
// ---------------------------------------------------------------------------
__global__ __launch_bounds__(256) void machine_kernel(
    const float* __restrict__ machine_f, const int* __restrict__ machine_a,
    const float* __restrict__ hlast, const float* __restrict__ jm,
    const float* __restrict__ mfe_W, const float* __restrict__ mfe_b,
    const float* __restrict__ n2_g, const float* __restrict__ n2_b,
    const float* __restrict__ me_W, const float* __restrict__ me_b,
    const float* __restrict__ n3_g, const float* __restrict__ n3_b,
    const float* __restrict__ mgW, const float* __restrict__ mga,
    const float* __restrict__ mng, const float* __restrict__ mnb,
    float* __restrict__ outp)
{
  __shared__ float mf[256];
  __shared__ int adjs[256];
  __shared__ __align__(16) float ctx[16 * CPAD];
  __shared__ __align__(16) float mfh[16 * CPAD];
  __shared__ __align__(16) float cur[16 * CPAD];
  __shared__ __align__(16) float tmp[16 * CPAD];
  __shared__ __align__(16) float prevb[16 * CPAD];
  __shared__ float pm[16 * PPAD];
  __shared__ float f1s[16], f2s[16];

  const int b = blockIdx.x;
  const int tid = threadIdx.x;
  const int i = tid >> 4;
  const int jb = tid & 15;
  const int j0 = jb << 3;

  mf[tid] = machine_f[(size_t)b * 256 + tid];
  adjs[tid] = machine_a[(size_t)b * 256 + tid];
  {
    const float* src = (i < 8) ? (hlast + ((size_t)i * B_ + b) * H_)
                               : (jm + ((size_t)b * M_ + (i - 8)) * H_);
    *(float4*)(ctx + i * CPAD + j0) = ((const float4*)src)[jb * 2];
    *(float4*)(ctx + i * CPAD + j0 + 4) = ((const float4*)src)[jb * 2 + 1];
  }
  __syncthreads();

  {
    float acc[8];
#pragma unroll
    for (int c = 0; c < 8; ++c) acc[c] = 0.f;
#pragma unroll
    for (int k = 0; k < MF_; ++k) {
      float xv = mf[i * 16 + k];
      float4 wa = *(const float4*)(mfe_W + (size_t)k * H_ + j0);
      float4 wb = *(const float4*)(mfe_W + (size_t)k * H_ + j0 + 4);
      fma8(acc, xv, wa, wb);
    }
#pragma unroll
    for (int c = 0; c < 8; ++c) acc[c] += mfe_b[j0 + c];
    ln_row(acc, n2_g, n2_b, j0);
#pragma unroll
    for (int c = 0; c < 8; ++c) mfh[i * CPAD + j0 + c] = tanhf(acc[c]);
  }
  __syncthreads();

  {
    float acc[8];
#pragma unroll
    for (int c = 0; c < 8; ++c) acc[c] = 0.f;
#pragma unroll 4
    for (int k = 0; k < H_; ++k) {
      float xv = mfh[i * CPAD + k];
      float4 wa = *(const float4*)(me_W + (size_t)k * H_ + j0);
      float4 wb = *(const float4*)(me_W + (size_t)k * H_ + j0 + 4);
      fma8(acc, xv, wa, wb);
    }
#pragma unroll 4
    for (int k = 0; k < H_; ++k) {
      float xv = ctx[i * CPAD + k];
      float4 wa = *(const float4*)(me_W + (size_t)(128 + k) * H_ + j0);
      float4 wb = *(const float4*)(me_W + (size_t)(128 + k) * H_ + j0 + 4);
      fma8(acc, xv, wa, wb);
    }
#pragma unroll
    for (int c = 0; c < 8; ++c) acc[c] += me_b[j0 + c];
    ln_row(acc, n3_g, n3_b, j0);
#pragma unroll
    for (int c = 0; c < 8; ++c) cur[i * CPAD + j0 + c] = tanhf(acc[c]);
  }
  __syncthreads();

  for (int l = 0; l < 4; ++l) {
    const float* W = mgW + (size_t)l * H_ * H_;
    const float* a0 = mga + l * 256;
    const float* a1 = a0 + 128;

    float acc[8];
#pragma unroll
    for (int c = 0; c < 8; ++c) acc[c] = 0.f;
#pragma unroll 4
    for (int k = 0; k < H_; ++k) {
      float xv = cur[i * CPAD + k];
      float4 wa = *(const float4*)(W + (size_t)k * H_ + j0);
      float4 wb = *(const float4*)(W + (size_t)k * H_ + j0 + 4);
      fma8(acc, xv, wa, wb);
    }
    *(float4*)(tmp + i * CPAD + j0) = make_float4(acc[0], acc[1], acc[2], acc[3]);
    *(float4*)(tmp + i * CPAD + j0 + 4) = make_float4(acc[4], acc[5], acc[6], acc[7]);

    float p1 = 0.f, p2 = 0.f;
#pragma unroll
    for (int c = 0; c < 8; ++c) {
      p1 = fmaf(acc[c], a0[j0 + c], p1);
      p2 = fmaf(acc[c], a1[j0 + c], p2);
    }
    p1 = grp16_sum(p1); p2 = grp16_sum(p2);
    if (jb == 0) { f1s[i] = p1; f2s[i] = p2; }
    __syncthreads();

    {
      int jc = jb;
      float e = f1s[i] + f2s[jc];
      e = (e >= 0.f) ? e : 0.2f * e;
      if (adjs[i * 16 + jc] <= 0) e = -1e9f;
      float mxv = grp16_max(e);
      float ex = __expf(e - mxv);
      float smv = grp16_sum(ex);
      pm[i * PPAD + jc] = ex / smv;
    }
    __syncthreads();

    float o[8];
#pragma unroll
    for (int c = 0; c < 8; ++c) o[c] = 0.f;
#pragma unroll
    for (int k = 0; k < 16; ++k) {
      float pv = pm[i * PPAD + k];
      float4 ha = *(const float4*)(tmp + k * CPAD + j0);
      float4 hb = *(const float4*)(tmp + k * CPAD + j0 + 4);
      fma8(o, pv, ha, hb);
    }
    ln_row(o, mng + l * H_, mnb + l * H_, j0);
#pragma unroll
    for (int c = 0; c < 8; ++c) {
      float v = o[c] + ((l > 0) ? prevb[i * CPAD + j0 + c] : 0.f);
      v = tanhf(v);
      cur[i * CPAD + j0 + c] = v;
      prevb[i * CPAD + j0 + c] = v;
    }
    __syncthreads();
  }

  if (tid < 128) {
    float s = 0.f;
#pragma unroll
    for (int r = 0; r < 16; ++r) s += cur[r * CPAD + tid];
    outp[(size_t)b * H_ + tid] = s * (1.f / 16.f);
  }
}

// ---------------------------------------------------------------------------
extern "C" void kernel_launch(void* const* d_in, const int* in_sizes, int n_in,
                              void* d_out, int out_size, void* d_ws, size_t ws_size,
                              hipStream_t stream) {
  const float* j_stages_f  = (const float*)d_in[0];
  const int*   j_stages_a  = (const int*)d_in[1];
  const float* j_machine_f = (const float*)d_in[2];
  const int*   j_machine_a = (const int*)d_in[3];
  const float* machine_f   = (const float*)d_in[4];
  const int*   machine_a   = (const int*)d_in[5];
  const float* jg1_W       = (const float*)d_in[6];
  const float* jgW         = (const float*)d_in[7];
  const float* jga         = (const float*)d_in[8];
  const float* lstm_Wih    = (const float*)d_in[9];
  const float* lstm_Whh    = (const float*)d_in[10];
  const float* lstm_b      = (const float*)d_in[11];
  const float* mfe_W       = (const float*)d_in[12];
  const float* mfe_b       = (const float*)d_in[13];
  const float* n2_g        = (const float*)d_in[14];
  const float* n2_b        = (const float*)d_in[15];
  const float* me_W        = (const float*)d_in[16];
  const float* me_b        = (const float*)d_in[17];
  const float* n3_g        = (const float*)d_in[18];
  const float* n3_b        = (const float*)d_in[19];
  const float* mgW         = (const float*)d_in[20];
  const float* mga         = (const float*)d_in[21];
  const float* mng         = (const float*)d_in[22];
  const float* mnb         = (const float*)d_in[23];
  float* out = (float*)d_out;

  // workspace layout (floats): stage_emb | jm | hlast | xs
  float* stage_emb = (float*)d_ws;                  // G1*128
  float* jm        = stage_emb + (size_t)G1_ * H_;  // G2*128
  float* hlast     = jm + (size_t)G2_ * H_;         // SB*128
  float* xs        = hlast + (size_t)SB_ * H_;      // T*SB*512
  // packed weights live at the start of the xs region: xs is only written by
  // xs_kernel, which runs AFTER both gat_mfma_kernel launches complete.
  u16* wpk0 = (u16*)xs;
  u16* wpkL = wpk0 + 4096;

  pack_w_kernel<<<208, 256, 0, stream>>>(jg1_W, jgW, wpk0, wpkL);
  gat_mfma_kernel<<<G1_ / 4, 256, 0, stream>>>(j_stages_f, j_stages_a, wpk0, wpkL, jga, stage_emb);
  gat_mfma_kernel<<<G2_ / 4, 256, 0, stream>>>(j_machine_f, j_machine_a, wpk0, wpkL, jga, jm);
  xs_kernel<<<G1_ / 16, 512, 0, stream>>>(stage_emb, lstm_Wih, lstm_b, xs);
  lstm_kernel<<<SB_, 512, 0, stream>>>(xs, lstm_Whh, hlast);
  machine_kernel<<<B_, 256, 0, stream>>>(machine_f, machine_a, hlast, jm,
                                         mfe_W, mfe_b, n2_g, n2_b, me_W, me_b,
                                         n3_g, n3_b, mgW, mga, mng, mnb, out);
}

// Round 3
// 531.685 us; speedup vs baseline: 7.2686x; 1.8816x over previous
//
#include <hip/hip_runtime.h>
#include <hip/hip_bf16.h>
#include <math.h>

#define S_ 8
#define B_ 64
#define T_ 64
#define N_ 16
#define FJ_ 32
#define H_ 128
#define MF_ 16
#define M_ 8
#define SB_ 512    // S*B
#define G1_ 32768  // S*B*T
#define G2_ 512    // B*M

#define CPAD 132   // padded stride for [16][128] f32 tile (machine kernel)
#define PPAD 17

typedef short bf16x8 __attribute__((ext_vector_type(8)));
typedef float f32x4 __attribute__((ext_vector_type(4)));
typedef unsigned short u16;

__device__ __forceinline__ u16 f2bf(float f) {
  union { float f; unsigned u; } v; v.f = f;
  unsigned r = v.u + 0x7FFFu + ((v.u >> 16) & 1u);
  return (u16)(r >> 16);
}
__device__ __forceinline__ unsigned packbf2(float lo, float hi) {
  return (unsigned)f2bf(lo) | ((unsigned)f2bf(hi) << 16);
}
__device__ __forceinline__ float ftanh(float x) {
  float e = __expf(2.f * x);
  return 1.f - 2.f / (e + 1.f);
}
__device__ __forceinline__ float sigmoidf_(float x) { return 1.f / (1.f + __expf(-x)); }

__device__ __forceinline__ void fma8(float (&acc)[8], float xv, float4 wa, float4 wb) {
  acc[0] = fmaf(xv, wa.x, acc[0]); acc[1] = fmaf(xv, wa.y, acc[1]);
  acc[2] = fmaf(xv, wa.z, acc[2]); acc[3] = fmaf(xv, wa.w, acc[3]);
  acc[4] = fmaf(xv, wb.x, acc[4]); acc[5] = fmaf(xv, wb.y, acc[5]);
  acc[6] = fmaf(xv, wb.z, acc[6]); acc[7] = fmaf(xv, wb.w, acc[7]);
}
__device__ __forceinline__ float grp16_sum(float v) {
#pragma unroll
  for (int m = 1; m < 16; m <<= 1) v += __shfl_xor(v, m);
  return v;
}
__device__ __forceinline__ float grp16_max(float v) {
#pragma unroll
  for (int m = 1; m < 16; m <<= 1) v = fmaxf(v, __shfl_xor(v, m));
  return v;
}
__device__ __forceinline__ void ln_row(float (&v)[8], const float* gw, const float* bw, int j0) {
  float s1 = 0.f, s2 = 0.f;
#pragma unroll
  for (int c = 0; c < 8; ++c) { s1 += v[c]; s2 += v[c] * v[c]; }
  s1 = grp16_sum(s1); s2 = grp16_sum(s2);
  float mu = s1 * (1.f / 128.f);
  float var = s2 * (1.f / 128.f) - mu * mu;
  float rstd = rsqrtf(var + 1e-5f);
#pragma unroll
  for (int c = 0; c < 8; ++c) v[c] = (v[c] - mu) * rstd * gw[j0 + c] + bw[j0 + c];
}

// ---------------------------------------------------------------------------
// Pack weights into per-lane MFMA fragment order (bf16).
// wpk0 : layer-0 W as 9 B-tiles (tile 8 = [W@a0, W@a1, 0...]),  9*64*8
// wpkL : layers 1..3, 9 tiles x 4 kk,  3*9*4*64*8
// wpkIH/wpkHH : LSTM weights as A-fragments, 32 tiles x 4 kk,  32*4*64*8 each
// ---------------------------------------------------------------------------
__global__ __launch_bounds__(256) void pack_w_kernel(
    const float* __restrict__ W0, const float* __restrict__ W123,
    const float* __restrict__ jga,
    const float* __restrict__ Wih, const float* __restrict__ Whh,
    u16* __restrict__ wpk0, u16* __restrict__ wpkL,
    u16* __restrict__ wpkIH, u16* __restrict__ wpkHH)
{
  int idx = blockIdx.x * 256 + threadIdx.x;
  if (idx < 4608) {
    int e = idx & 7, l = (idx >> 3) & 63, n = idx >> 9;
    int q = l >> 4, cc = l & 15;
    int k = q * 8 + e;  // < 32
    float v = 0.f;
    if (n < 8) v = W0[k * 128 + 16 * n + cc];
    else if (cc < 2) {
      const float* a = jga + cc * 128;
      float s = 0.f;
      for (int j = 0; j < 128; ++j) s += W0[k * 128 + j] * a[j];
      v = s;
    }
    wpk0[idx] = f2bf(v);
  } else if (idx < 59904) {
    int id = idx - 4608;
    int e = id & 7, l = (id >> 3) & 63, kk = (id >> 9) & 3;
    int id2 = id >> 11;  // layer*9 + n
    int n = id2 % 9, layer = id2 / 9;
    int q = l >> 4, cc = l & 15;
    int k = kk * 32 + q * 8 + e;
    const float* W = W123 + (size_t)layer * 16384;
    float v = 0.f;
    if (n < 8) v = W[k * 128 + 16 * n + cc];
    else if (cc < 2) {
      const float* a = jga + (layer + 1) * 256 + cc * 128;
      float s = 0.f;
      for (int j = 0; j < 128; ++j) s += W[k * 128 + j] * a[j];
      v = s;
    }
    wpkL[id] = f2bf(v);
  } else if (idx < 125440) {
    int id = idx - 59904;
    int e = id & 7, l = (id >> 3) & 63, kk = (id >> 9) & 3, n = id >> 11;
    int gate = 16 * n + (l & 15), k = 32 * kk + 8 * (l >> 4) + e;
    wpkIH[id] = f2bf(Wih[gate * 128 + k]);
  } else if (idx < 190976) {
    int id = idx - 125440;
    int e = id & 7, l = (id >> 3) & 63, kk = (id >> 9) & 3, n = id >> 11;
    int gate = 16 * n + (l & 15), k = 32 * kk + 8 * (l >> 4) + e;
    wpkHH[id] = f2bf(Whh[gate * 128 + k]);
  }
}

// ---------------------------------------------------------------------------
// GAT encoder: ONE WAVE PER GRAPH (4 graphs / 256-thr block). f1/f2 folded
// into MFMA tile 8; PV B-frags via batched LDS b64-write/b128-read.
// Shared per-wave region reused: activation tile [16][136]u16 (phase A) and
// h-tile buffer [8 tiles][16 cols][12 dwords] (phase B) - disjoint lifetimes.
// ---------------------------------------------------------------------------
__global__ __launch_bounds__(256) void gat_mfma_kernel(
    const float* __restrict__ xin,   // [G,16,32]
    const int* __restrict__ adjin,   // [G,16,16]
    const u16* __restrict__ wpk0, const u16* __restrict__ wpkL,
    float* __restrict__ outm,        // [G,128] f32
    u16* __restrict__ outbf)         // [G,128] bf16
{
  __shared__ __align__(16) char region[4][6144];
  __shared__ __align__(16) float fbuf[4][32];

  const int wv = threadIdx.x >> 6;
  const int l = threadIdx.x & 63;
  const int g = blockIdx.x * 4 + wv;
  const int c = l & 15, q = l >> 4, qq = q & 1;
  u16* cw = (u16*)region[wv];
  unsigned* hb = (unsigned*)region[wv];
  float* fb = fbuf[wv];

  // adjacency mask bits: row i=c, cols j = 8*qq + e
  int adjm;
  {
    const int* ar = adjin + (size_t)g * 256 + c * 16 + 8 * qq;
    int4 A1 = *(const int4*)ar;
    int4 A2 = *(const int4*)(ar + 4);
    adjm = (A1.x > 0) | ((A1.y > 0) << 1) | ((A1.z > 0) << 2) | ((A1.w > 0) << 3) |
           ((A2.x > 0) << 4) | ((A2.y > 0) << 5) | ((A2.z > 0) << 6) | ((A2.w > 0) << 7);
  }

  f32x4 res[8];
#pragma unroll
  for (int n = 0; n < 8; ++n) res[n] = (f32x4){0.f, 0.f, 0.f, 0.f};

#pragma unroll 1
  for (int layer = 0; layer < 4; ++layer) {
    bf16x8 afr[4];
    const u16* wl;
    if (layer == 0) {
      wl = wpk0;
      const float* xg = xin + (size_t)g * 512 + c * 32 + q * 8;
      float4 x1 = *(const float4*)xg;
      float4 x2 = *(const float4*)(xg + 4);
      union { bf16x8 v; u16 s[8]; } u;
      u.s[0] = f2bf(x1.x); u.s[1] = f2bf(x1.y); u.s[2] = f2bf(x1.z); u.s[3] = f2bf(x1.w);
      u.s[4] = f2bf(x2.x); u.s[5] = f2bf(x2.y); u.s[6] = f2bf(x2.z); u.s[7] = f2bf(x2.w);
      afr[0] = u.v;
    } else {
      wl = wpkL + (size_t)(layer - 1) * 18432;
#pragma unroll
      for (int kk = 0; kk < 4; ++kk)
        afr[kk] = *(const bf16x8*)(cw + c * 136 + kk * 32 + q * 8);
    }

    // ---- h = x @ W tiles 0..7; pack rows to bf16 pairs into h-tile LDS ----
#pragma unroll
    for (int n = 0; n < 8; ++n) {
      f32x4 acc = (f32x4){0.f, 0.f, 0.f, 0.f};
      if (layer == 0) {
        bf16x8 wf = *(const bf16x8*)(wl + ((size_t)n * 64 + l) * 8);
        acc = __builtin_amdgcn_mfma_f32_16x16x32_bf16(afr[0], wf, acc, 0, 0, 0);
      } else {
#pragma unroll
        for (int kk = 0; kk < 4; ++kk) {
          bf16x8 wf = *(const bf16x8*)(wl + ((size_t)(n * 4 + kk) * 64 + l) * 8);
          acc = __builtin_amdgcn_mfma_f32_16x16x32_bf16(afr[kk], wf, acc, 0, 0, 0);
        }
      }
      uint2 hv2;
      hv2.x = packbf2(acc[0], acc[1]);  // rows 4q+0,4q+1 at col 16n+c
      hv2.y = packbf2(acc[2], acc[3]);  // rows 4q+2,4q+3
      *(uint2*)(hb + n * 192 + c * 12 + 2 * q) = hv2;
    }

    // ---- f-tile (n=8): col0 = h@a0, col1 = h@a1 via W@a fold ----
    {
      f32x4 f8 = (f32x4){0.f, 0.f, 0.f, 0.f};
      if (layer == 0) {
        bf16x8 wf = *(const bf16x8*)(wl + ((size_t)8 * 64 + l) * 8);
        f8 = __builtin_amdgcn_mfma_f32_16x16x32_bf16(afr[0], wf, f8, 0, 0, 0);
      } else {
#pragma unroll
        for (int kk = 0; kk < 4; ++kk) {
          bf16x8 wf = *(const bf16x8*)(wl + ((size_t)(8 * 4 + kk) * 64 + l) * 8);
          f8 = __builtin_amdgcn_mfma_f32_16x16x32_bf16(afr[kk], wf, f8, 0, 0, 0);
        }
      }
      if (c < 2) *(f32x4*)(fb + c * 16 + 4 * q) = f8;  // f1 -> fb[0..15], f2 -> fb[16..31]
    }

    // ---- softmax row i=c over j, laid out as P A-fragment (k=8q+e) ----
    float f1v = fb[c];
    float4 f2a = *(const float4*)&fb[16 + 8 * qq];
    float4 f2b = *(const float4*)&fb[16 + 8 * qq + 4];
    float ev[8] = {f1v + f2a.x, f1v + f2a.y, f1v + f2a.z, f1v + f2a.w,
                   f1v + f2b.x, f1v + f2b.y, f1v + f2b.z, f1v + f2b.w};
#pragma unroll
    for (int e = 0; e < 8; ++e) {
      float v = ev[e];
      v = (v >= 0.f) ? v : 0.2f * v;
      ev[e] = ((adjm >> e) & 1) ? v : -1e9f;
    }
    float mx = ev[0];
#pragma unroll
    for (int e = 1; e < 8; ++e) mx = fmaxf(mx, ev[e]);
    mx = fmaxf(mx, __shfl_xor(mx, 16));
    float sm = 0.f;
#pragma unroll
    for (int e = 0; e < 8; ++e) { ev[e] = __expf(ev[e] - mx); sm += ev[e]; }
    sm += __shfl_xor(sm, 16);
    float zinv = (q < 2) ? (1.f / sm) : 0.f;  // groups 2,3 hold K-padding zeros
    union { bf16x8 v; u16 s[8]; } pu;
#pragma unroll
    for (int e = 0; e < 8; ++e) pu.s[e] = f2bf(ev[e] * zinv);
    bf16x8 pfrag = pu.v;

    // ---- O = P @ h (+residual) -> tanh ----
#pragma unroll
    for (int n = 0; n < 8; ++n) {
      union { bf16x8 v; uint4 u; } bu;
      bu.u = make_uint4(0u, 0u, 0u, 0u);
      if (q < 2) bu.u = *(const uint4*)(hb + n * 192 + c * 12 + 4 * q);
      f32x4 o = (layer > 0) ? res[n] : (f32x4){0.f, 0.f, 0.f, 0.f};
      o = __builtin_amdgcn_mfma_f32_16x16x32_bf16(pfrag, bu.v, o, 0, 0, 0);
      f32x4 t;
      t[0] = ftanh(o[0]); t[1] = ftanh(o[1]); t[2] = ftanh(o[2]); t[3] = ftanh(o[3]);
      res[n] = t;
    }
    // write next-layer activations AFTER all h-tile reads (region is shared)
    if (layer < 3) {
#pragma unroll
      for (int n = 0; n < 8; ++n)
#pragma unroll
        for (int r = 0; r < 4; ++r)
          cw[(4 * q + r) * 136 + 16 * n + c] = f2bf(res[n][r]);
    }
  }

  // ---- mean over 16 nodes; write f32 and bf16 ----
#pragma unroll
  for (int n = 0; n < 8; ++n) {
    float s = res[n][0] + res[n][1] + res[n][2] + res[n][3];
    s += __shfl_xor(s, 16);
    s += __shfl_xor(s, 32);
    if (q == 0) {
      float v = s * 0.0625f;
      outm[(size_t)g * 128 + 16 * n + c] = v;
      outbf[(size_t)g * 128 + 16 * n + c] = f2bf(v);
    }
  }
}

// ---------------------------------------------------------------------------
// Fused xs+LSTM via MFMA. 32 blocks x 512 thr; block owns 16 sequences.
// Gates computed transposed: G^T[gate][seq] = Wih@x^T + Whh@h^T; wave w owns
// gate tiles {w, 8+w, 16+w, 24+w} so (i,f,g,o) for gate-slot j=16w+4q+r,
// seq=c are all lane-local. Wih/Whh A-frags register-resident for all steps.
// h carried bf16, k-pair-interleaved in LDS: hbuf[k>>1][seq].
// ---------------------------------------------------------------------------
__global__ __launch_bounds__(512) void lstm_fused_kernel(
    const u16* __restrict__ emb_bf,  // [SB*T,128] bf16
    const u16* __restrict__ wpkIH, const u16* __restrict__ wpkHH,
    const float* __restrict__ bvec,  // [512]
    float* __restrict__ hlast)       // [SB,128]
{
  __shared__ unsigned hbuf[2][1024];
  const int tid = threadIdx.x;
  const int w = tid >> 6, l = tid & 63;
  const int c = l & 15, q = l >> 4;
  const int seq0 = blockIdx.x * 16;

  bf16x8 aih[4][4], ahh[4][4];
#pragma unroll
  for (int m = 0; m < 4; ++m)
#pragma unroll
    for (int kk = 0; kk < 4; ++kk) {
      int n = 8 * m + w;
      aih[m][kk] = *(const bf16x8*)(wpkIH + ((size_t)((n * 4 + kk) * 64 + l)) * 8);
      ahh[m][kk] = *(const bf16x8*)(wpkHH + ((size_t)((n * 4 + kk) * 64 + l)) * 8);
    }
  float bias[4][4];
#pragma unroll
  for (int m = 0; m < 4; ++m)
#pragma unroll
    for (int r = 0; r < 4; ++r) bias[m][r] = bvec[128 * m + 16 * w + 4 * q + r];

  hbuf[0][tid] = 0u;
  hbuf[0][512 + tid] = 0u;
  __syncthreads();

  float cst[4] = {0.f, 0.f, 0.f, 0.f};
  float hv[4] = {0.f, 0.f, 0.f, 0.f};
  int pb = 0;
#pragma unroll 1
  for (int t = 0; t < T_; ++t) {
    bf16x8 xf[4], hf[4];
    const u16* xr = emb_bf + (((size_t)(seq0 + c)) * 64 + t) * 128 + q * 8;
#pragma unroll
    for (int kk = 0; kk < 4; ++kk) xf[kk] = *(const bf16x8*)(xr + kk * 32);
#pragma unroll
    for (int kk = 0; kk < 4; ++kk) {
      union { bf16x8 v; unsigned u[4]; } hu;
#pragma unroll
      for (int ep = 0; ep < 4; ++ep)
        hu.u[ep] = hbuf[pb][(16 * kk + 4 * q + ep) * 16 + c];
      hf[kk] = hu.v;
    }
    f32x4 acc[4];
#pragma unroll
    for (int m = 0; m < 4; ++m) {
      f32x4 a = (f32x4){0.f, 0.f, 0.f, 0.f};
#pragma unroll
      for (int kk = 0; kk < 4; ++kk)
        a = __builtin_amdgcn_mfma_f32_16x16x32_bf16(aih[m][kk], xf[kk], a, 0, 0, 0);
#pragma unroll
      for (int kk = 0; kk < 4; ++kk)
        a = __builtin_amdgcn_mfma_f32_16x16x32_bf16(ahh[m][kk], hf[kk], a, 0, 0, 0);
      acc[m] = a;
    }
#pragma unroll
    for (int r = 0; r < 4; ++r) {
      float ig = acc[0][r] + bias[0][r];
      float fg = acc[1][r] + bias[1][r];
      float gg = acc[2][r] + bias[2][r];
      float og = acc[3][r] + bias[3][r];
      cst[r] = sigmoidf_(fg) * cst[r] + sigmoidf_(ig) * ftanh(gg);
      hv[r] = sigmoidf_(og) * ftanh(cst[r]);
    }
    hbuf[pb ^ 1][(8 * w + 2 * q) * 16 + c] = packbf2(hv[0], hv[1]);
    hbuf[pb ^ 1][(8 * w + 2 * q + 1) * 16 + c] = packbf2(hv[2], hv[3]);
    __syncthreads();
    pb ^= 1;
  }
#pragma unroll
  for (int r = 0; r < 4; ++r)
    hlast[((size_t)(seq0 + c)) * 128 + 16 * w + 4 * q + r] = hv[r];
}

// ---------------------------------------------------------------------------
// Kernel D: fused machine-side pipeline. One block per batch element b.
// ---------------------------------------------------------------------------
__global__ __launch_bounds__(256) void machine_kernel(
    const float* __restrict__ machine_f, const int* __restrict__ machine_a,
    const float* __restrict__ hlast, const float* __restrict__ jm,
    const float* __restrict__ mfe_W, const float* __restrict__ mfe_b,
    const float* __restrict__ n2_g, const float* __restrict__ n2_b,
    const float* __restrict__ me_W, const float* __restrict__ me_b,
    const float* __restrict__ n3_g, const float* __restrict__ n3_b,
    const float* __restrict__ mgW, const float* __restrict__ mga,
    const float* __restrict__ mng, const float* __restrict__ mnb,
    float* __restrict__ outp)
{
  __shared__ float mf[256];
  __shared__ int adjs[256];
  __shared__ __align__(16) float ctx[16 * CPAD];
  __shared__ __align__(16) float mfh[16 * CPAD];
  __shared__ __align__(16) float cur[16 * CPAD];
  __shared__ __align__(16) float tmp[16 * CPAD];
  __shared__ __align__(16) float prevb[16 * CPAD];
  __shared__ float pm[16 * PPAD];
  __shared__ float f1s[16], f2s[16];

  const int b = blockIdx.x;
  const int tid = threadIdx.x;
  const int i = tid >> 4;
  const int jb = tid & 15;
  const int j0 = jb << 3;

  mf[tid] = machine_f[(size_t)b * 256 + tid];
  adjs[tid] = machine_a[(size_t)b * 256 + tid];
  {
    const float* src = (i < 8) ? (hlast + ((size_t)i * B_ + b) * H_)
                               : (jm + ((size_t)b * M_ + (i - 8)) * H_);
    *(float4*)(ctx + i * CPAD + j0) = ((const float4*)src)[jb * 2];
    *(float4*)(ctx + i * CPAD + j0 + 4) = ((const float4*)src)[jb * 2 + 1];
  }
  __syncthreads();

  {
    float acc[8];
#pragma unroll
    for (int c = 0; c < 8; ++c) acc[c] = 0.f;
#pragma unroll
    for (int k = 0; k < MF_; ++k) {
      float xv = mf[i * 16 + k];
      float4 wa = *(const float4*)(mfe_W + (size_t)k * H_ + j0);
      float4 wb = *(const float4*)(mfe_W + (size_t)k * H_ + j0 + 4);
      fma8(acc, xv, wa, wb);
    }
#pragma unroll
    for (int c = 0; c < 8; ++c) acc[c] += mfe_b[j0 + c];
    ln_row(acc, n2_g, n2_b, j0);
#pragma unroll
    for (int c = 0; c < 8; ++c) mfh[i * CPAD + j0 + c] = tanhf(acc[c]);
  }
  __syncthreads();

  {
    float acc[8];
#pragma unroll
    for (int c = 0; c < 8; ++c) acc[c] = 0.f;
#pragma unroll 4
    for (int k = 0; k < H_; ++k) {
      float xv = mfh[i * CPAD + k];
      float4 wa = *(const float4*)(me_W + (size_t)k * H_ + j0);
      float4 wb = *(const float4*)(me_W + (size_t)k * H_ + j0 + 4);
      fma8(acc, xv, wa, wb);
    }
#pragma unroll 4
    for (int k = 0; k < H_; ++k) {
      float xv = ctx[i * CPAD + k];
      float4 wa = *(const float4*)(me_W + (size_t)(128 + k) * H_ + j0);
      float4 wb = *(const float4*)(me_W + (size_t)(128 + k) * H_ + j0 + 4);
      fma8(acc, xv, wa, wb);
    }
#pragma unroll
    for (int c = 0; c < 8; ++c) acc[c] += me_b[j0 + c];
    ln_row(acc, n3_g, n3_b, j0);
#pragma unroll
    for (int c = 0; c < 8; ++c) cur[i * CPAD + j0 + c] = tanhf(acc[c]);
  }
  __syncthreads();

  for (int l = 0; l < 4; ++l) {
    const float* W = mgW + (size_t)l * H_ * H_;
    const float* a0 = mga + l * 256;
    const float* a1 = a0 + 128;

    float acc[8];
#pragma unroll
    for (int c = 0; c < 8; ++c) acc[c] = 0.f;
#pragma unroll 4
    for (int k = 0; k < H_; ++k) {
      float xv = cur[i * CPAD + k];
      float4 wa = *(const float4*)(W + (size_t)k * H_ + j0);
      float4 wb = *(const float4*)(W + (size_t)k * H_ + j0 + 4);
      fma8(acc, xv, wa, wb);
    }
    *(float4*)(tmp + i * CPAD + j0) = make_float4(acc[0], acc[1], acc[2], acc[3]);
    *(float4*)(tmp + i * CPAD + j0 + 4) = make_float4(acc[4], acc[5], acc[6], acc[7]);

    float p1 = 0.f, p2 = 0.f;
#pragma unroll
    for (int c = 0; c < 8; ++c) {
      p1 = fmaf(acc[c], a0[j0 + c], p1);
      p2 = fmaf(acc[c], a1[j0 + c], p2);
    }
    p1 = grp16_sum(p1); p2 = grp16_sum(p2);
    if (jb == 0) { f1s[i] = p1; f2s[i] = p2; }
    __syncthreads();

    {
      int jc = jb;
      float e = f1s[i] + f2s[jc];
      e = (e >= 0.f) ? e : 0.2f * e;
      if (adjs[i * 16 + jc] <= 0) e = -1e9f;
      float mxv = grp16_max(e);
      float ex = __expf(e - mxv);
      float smv = grp16_sum(ex);
      pm[i * PPAD + jc] = ex / smv;
    }
    __syncthreads();

    float o[8];
#pragma unroll
    for (int c = 0; c < 8; ++c) o[c] = 0.f;
#pragma unroll
    for (int k = 0; k < 16; ++k) {
      float pv = pm[i * PPAD + k];
      float4 ha = *(const float4*)(tmp + k * CPAD + j0);
      float4 hb = *(const float4*)(tmp + k * CPAD + j0 + 4);
      fma8(o, pv, ha, hb);
    }
    ln_row(o, mng + l * H_, mnb + l * H_, j0);
#pragma unroll
    for (int c = 0; c < 8; ++c) {
      float v = o[c] + ((l > 0) ? prevb[i * CPAD + j0 + c] : 0.f);
      v = tanhf(v);
      cur[i * CPAD + j0 + c] = v;
      prevb[i * CPAD + j0 + c] = v;
    }
    __syncthreads();
  }

  if (tid < 128) {
    float s = 0.f;
#pragma unroll
    for (int r = 0; r < 16; ++r) s += cur[r * CPAD + tid];
    outp[(size_t)b * H_ + tid] = s * (1.f / 16.f);
  }
}

// ---------------------------------------------------------------------------
extern "C" void kernel_launch(void* const* d_in, const int* in_sizes, int n_in,
                              void* d_out, int out_size, void* d_ws, size_t ws_size,
                              hipStream_t stream) {
  const float* j_stages_f  = (const float*)d_in[0];
  const int*   j_stages_a  = (const int*)d_in[1];
  const float* j_machine_f = (const float*)d_in[2];
  const int*   j_machine_a = (const int*)d_in[3];
  const float* machine_f   = (const float*)d_in[4];
  const int*   machine_a   = (const int*)d_in[5];
  const float* jg1_W       = (const float*)d_in[6];
  const float* jgW         = (const float*)d_in[7];
  const float* jga         = (const float*)d_in[8];
  const float* lstm_Wih    = (const float*)d_in[9];
  const float* lstm_Whh    = (const float*)d_in[10];
  const float* lstm_b      = (const float*)d_in[11];
  const float* mfe_W       = (const float*)d_in[12];
  const float* mfe_b       = (const float*)d_in[13];
  const float* n2_g        = (const float*)d_in[14];
  const float* n2_b        = (const float*)d_in[15];
  const float* me_W        = (const float*)d_in[16];
  const float* me_b        = (const float*)d_in[17];
  const float* n3_g        = (const float*)d_in[18];
  const float* n3_b        = (const float*)d_in[19];
  const float* mgW         = (const float*)d_in[20];
  const float* mga         = (const float*)d_in[21];
  const float* mng         = (const float*)d_in[22];
  const float* mnb         = (const float*)d_in[23];
  float* out = (float*)d_out;

  // workspace layout (bytes)
  char* ws = (char*)d_ws;
  u16*   emb_bf  = (u16*)ws;                          // 32768*128*2 = 8388608
  u16*   jmbf    = (u16*)(ws + 8388608);              // 512*128*2   = 131072
  float* jm      = (float*)(ws + 8519680);            // 512*128*4   = 262144
  float* hlast   = (float*)(ws + 8781824);            // 512*128*4   = 262144
  float* outm_s  = (float*)(ws + 9043968);            // 32768*128*4 = 16777216
  u16*   wpk0    = (u16*)(ws + 25821184);             // 4608*2
  u16*   wpkL    = (u16*)(ws + 25830400);             // 55296*2
  u16*   wpkIH   = (u16*)(ws + 25940992);             // 65536*2
  u16*   wpkHH   = (u16*)(ws + 26072064);             // 65536*2 -> 26203136

  pack_w_kernel<<<746, 256, 0, stream>>>(jg1_W, jgW, jga, lstm_Wih, lstm_Whh,
                                         wpk0, wpkL, wpkIH, wpkHH);
  gat_mfma_kernel<<<G1_ / 4, 256, 0, stream>>>(j_stages_f, j_stages_a, wpk0, wpkL,
                                               outm_s, emb_bf);
  gat_mfma_kernel<<<G2_ / 4, 256, 0, stream>>>(j_machine_f, j_machine_a, wpk0, wpkL,
                                               jm, jmbf);
  lstm_fused_kernel<<<SB_ / 16, 512, 0, stream>>>(emb_bf, wpkIH, wpkHH, lstm_b, hlast);
  machine_kernel<<<B_, 256, 0, stream>>>(machine_f, machine_a, hlast, jm,
                                         mfe_W, mfe_b, n2_g, n2_b, me_W, me_b,
                                         n3_g, n3_b, mgW, mga, mng, mnb, out);
}